// Round 12
// baseline (714.054 us; speedup 1.0000x reference)
//
#include <hip/hip_runtime.h>

#define N_NODES 50000
#define N_EDGES 800000
#define N_GRAPHS 1024
#define IN_DIM 78
#define K1P 128           // IN_DIM padded to multiple of 64 (BK=64 GEMM)
#define HID 256
#define OUT_DIM 128

typedef unsigned short ushort_t;
typedef __attribute__((ext_vector_type(8))) short v8s;
typedef __attribute__((ext_vector_type(4))) float v4f;
typedef __attribute__((ext_vector_type(4))) unsigned int u4;
typedef __attribute__((ext_vector_type(2))) unsigned short us2;
typedef __attribute__((ext_vector_type(4))) unsigned short us4;
typedef __attribute__((ext_vector_type(8))) unsigned short us8;

__device__ __forceinline__ ushort_t f2bf(float f) {
    unsigned u = __float_as_uint(f);
    unsigned r = (u + 0x7fffu + ((u >> 16) & 1u)) >> 16;   // RNE
    return (ushort_t)r;
}
__device__ __forceinline__ float bf2f(ushort_t h) {
    return __uint_as_float((unsigned)h << 16);
}

// ------------- fused weight transpose+pad+bf16 for ALL weights (1 launch) ------
// segments (elements of transposed+padded [N][Kp] output):
//  w1r_t 256x128 @0        w1o_t 256x128 @32768
//  w2r_t 512x256 @65536    w2o_t 512x256 @196608
//  w3r_t 512x512 @327680   w3o_t 512x512 @589824
//  wfc_t 128x512 @851968   total 917504
__global__ __launch_bounds__(256)
void wt_all_kernel(const float* __restrict__ W1r, const float* __restrict__ W1o,
                   const float* __restrict__ W2r, const float* __restrict__ W2o,
                   const float* __restrict__ W3r, const float* __restrict__ W3o,
                   const float* __restrict__ Wfc, ushort_t* __restrict__ out)
{
    int i = blockIdx.x * 256 + threadIdx.x;
    if (i >= 917504) return;
    const float* W; int K, N, Kp, base;
    if      (i < 32768)  { W = W1r; K = IN_DIM; N = HID;     Kp = 128; base = 0; }
    else if (i < 65536)  { W = W1o; K = IN_DIM; N = HID;     Kp = 128; base = 32768; }
    else if (i < 196608) { W = W2r; K = HID;    N = 2 * HID; Kp = 256; base = 65536; }
    else if (i < 327680) { W = W2o; K = HID;    N = 2 * HID; Kp = 256; base = 196608; }
    else if (i < 589824) { W = W3r; K = 2*HID;  N = 2 * HID; Kp = 512; base = 327680; }
    else if (i < 851968) { W = W3o; K = 2*HID;  N = 2 * HID; Kp = 512; base = 589824; }
    else                 { W = Wfc; K = 2*HID;  N = OUT_DIM; Kp = 512; base = 851968; }
    int j = i - base;
    int n = j / Kp, k = j - n * Kp;
    float v = (k < K) ? W[(size_t)k * N + n] : 0.0f;
    out[i] = f2bf(v);
}

// ---------------- pad + cast activations: out[r][k<Kin?]=in, else 0 -----------
__global__ __launch_bounds__(256)
void pad_cast_kernel(const float* __restrict__ in, ushort_t* __restrict__ out,
                     int rows, int Kin, int Kout)
{
    int i = blockIdx.x * 256 + threadIdx.x;
    if (i >= rows * Kout) return;
    int r = i / Kout, k = i - r * Kout;
    out[i] = f2bf(k < Kin ? in[(size_t)r * Kin + k] : 0.0f);
}

// ---------------- CSR build ----------------------------------------------------
__global__ __launch_bounds__(256)
void hist_kernel(const int* __restrict__ dstI, int* __restrict__ deg, int nE)
{
    int e = blockIdx.x * 256 + threadIdx.x;
    if (e < nE) {
        int d = dstI[e];
        if ((unsigned)d < (unsigned)N_NODES) atomicAdd(&deg[d], 1);
    }
}

__global__ __launch_bounds__(1024)
void scan1_kernel(const int* __restrict__ deg, int* __restrict__ rowptr,
                  int* __restrict__ blocksum, int n)
{
    __shared__ int s[1024];
    int b = (int)blockIdx.x, t = (int)threadIdx.x;
    int i = b * 1024 + t;
    int v = (i < n) ? deg[i] : 0;
    s[t] = v;
    __syncthreads();
    for (int off = 1; off < 1024; off <<= 1) {
        int a = (t >= off) ? s[t - off] : 0;
        __syncthreads();
        s[t] += a;
        __syncthreads();
    }
    if (i < n) rowptr[i + 1] = s[t];      // block-local inclusive
    if (t == 1023) blocksum[b] = s[1023];
    if (b == 0 && t == 0) rowptr[0] = 0;
}

__global__ __launch_bounds__(64)
void scan2_kernel(int* __restrict__ blocksum, int nb)   // nb <= 64
{
    int t = (int)threadIdx.x;
    int v = (t < nb) ? blocksum[t] : 0;
    #pragma unroll
    for (int off = 1; off < 64; off <<= 1) {
        int a = __shfl_up(v, off, 64);
        if (t >= off) v += a;
    }
    if (t < nb) blocksum[t] = v;
}

__global__ __launch_bounds__(256)
void scan3_kernel(const int* __restrict__ blocksum, int* __restrict__ rowptr,
                  int* __restrict__ cursor, int n)
{
    int j = blockIdx.x * 256 + threadIdx.x;   // 0..n
    if (j > n) return;
    int v;
    if (j == 0) v = 0;
    else {
        int b = (j - 1) >> 10;
        v = rowptr[j] + (b >= 1 ? blocksum[b - 1] : 0);
    }
    rowptr[j] = v;
    if (j < n) cursor[j] = v;
}

__global__ __launch_bounds__(256)
void fill_kernel(const int* __restrict__ srcI, const int* __restrict__ dstI,
                 int* __restrict__ cursor, int* __restrict__ csr_src, int nE)
{
    int e = blockIdx.x * 256 + threadIdx.x;
    if (e < nE) {
        int d = dstI[e];
        int s = srcI[e];
        if ((unsigned)d < (unsigned)N_NODES && (unsigned)s < (unsigned)N_NODES) {
            int pos = atomicAdd(&cursor[d], 1);
            csr_src[pos] = s;
        }
    }
}

// ---------------- CSR aggregation, wave-per-node, 8-deep load pipeline ----------
template<int VPT> struct VecT;
template<> struct VecT<2> { using T = us2; };
template<> struct VecT<4> { using T = us4; };
template<> struct VecT<8> { using T = us8; };

template<int VPT>
__global__ __launch_bounds__(256)
void csr_agg_wave_kernel(const ushort_t* __restrict__ feat,
                         const int* __restrict__ rowptr,
                         const int* __restrict__ csr_src,
                         ushort_t* __restrict__ out, int Ds)
{
    using T = typename VecT<VPT>::T;
    const int wv   = (int)threadIdx.x >> 6;
    const int node = (int)blockIdx.x * 4 + wv;
    if (node >= N_NODES) return;
    const int lane = (int)threadIdx.x & 63;
    const int off0 = lane * VPT;
    const bool act = off0 < Ds;
    const int off  = act ? off0 : (Ds - VPT);

    const int e0 = rowptr[node], e1 = rowptr[node + 1];
    float acc[VPT];
    #pragma unroll
    for (int i = 0; i < VPT; ++i) acc[i] = 0.0f;

    int e = e0;
    for (; e + 8 <= e1; e += 8) {
        T r[8];
        #pragma unroll
        for (int u = 0; u < 8; ++u) {
            int s = csr_src[e + u];
            r[u] = *(const T*)(feat + (size_t)s * Ds + off);
        }
        #pragma unroll
        for (int u = 0; u < 8; ++u)
            #pragma unroll
            for (int i = 0; i < VPT; ++i) acc[i] += bf2f(r[u][i]);
    }
    for (; e + 4 <= e1; e += 4) {
        T r[4];
        #pragma unroll
        for (int u = 0; u < 4; ++u) {
            int s = csr_src[e + u];
            r[u] = *(const T*)(feat + (size_t)s * Ds + off);
        }
        #pragma unroll
        for (int u = 0; u < 4; ++u)
            #pragma unroll
            for (int i = 0; i < VPT; ++i) acc[i] += bf2f(r[u][i]);
    }
    for (; e < e1; ++e) {
        int s = csr_src[e];
        T r = *(const T*)(feat + (size_t)s * Ds + off);
        #pragma unroll
        for (int i = 0; i < VPT; ++i) acc[i] += bf2f(r[i]);
    }

    if (act) {
        T o;
        #pragma unroll
        for (int i = 0; i < VPT; ++i) o[i] = f2bf(acc[i]);
        *(T*)(out + (size_t)node * Ds + off0) = o;
    }
}

// ---------------- bf16 MFMA GEMM, BK=64 (barrier-drain amortized 2x) ------------
// out = act( A1@W1t^T + A2@W2t^T + bias ),  A*: bf16 [M][K], W*t: bf16 [Fo][K]
// Tile: 128 rows x (NT*32) cols, BK=64. 4 waves 2x2; wave = 64 x NT*16.
// Rationale (r11 post-mortem): every __syncthreads drains vmcnt(0) -> each
// k-step pays a full A-load round trip. BK=64 doubles MFMA+LDS work per
// barrier pair, paying that drain half as often. K must be multiple of 64.
template<int NT>
__global__ __launch_bounds__(256, 2)
void mfma_gemm_kernel(const ushort_t* __restrict__ A1,
                      const ushort_t* __restrict__ A2,
                      const ushort_t* __restrict__ W1t,
                      const ushort_t* __restrict__ W2t,
                      const float* __restrict__ bias,
                      void* __restrict__ outp,
                      int M, int K, int Fo, int relu, int out_bf16)
{
    constexpr int BN    = NT * 32;     // tile width
    constexpr int NBT   = NT * 2;      // B n-tiles of 16
    constexpr int BT_PW = NBT / 4;     // B-tiles staged per wave
    // tile layout: tile t at t*1024 elems, k-chunk c at +c*512, lane l at +l*8
    __shared__ __align__(16) ushort_t Al[8 * 1024];     // 16 KB
    __shared__ __align__(16) ushort_t Bl[NBT * 1024];   // NT=8: 32 KB
    const int tid = (int)threadIdx.x;
    const int l   = tid & 63;
    const int w   = tid >> 6;
    const int q   = l >> 4;
    const int r15 = l & 15;
    const int bm  = blockIdx.y * 128;
    const int bn  = blockIdx.x * BN;
    const int wm  = w >> 1, wn = w & 1;

    const int s1 = K >> 6;                       // BK=64 steps per pass
    const int nsteps = A2 ? (2 * s1) : s1;

    v4f acc[4][NT];
    #pragma unroll
    for (int mt = 0; mt < 4; ++mt)
        #pragma unroll
        for (int nt = 0; nt < NT; ++nt)
            acc[mt][nt] = (v4f){0.0f, 0.0f, 0.0f, 0.0f};

    u4 ra[2][2], rb[BT_PW][2];
    auto load_step = [&](int step) {
        const ushort_t* A  = (step >= s1) ? A2  : A1;
        const ushort_t* Bt = (step >= s1) ? W2t : W1t;
        const int k0 = ((step >= s1) ? (step - s1) : step) << 6;
        #pragma unroll
        for (int ii = 0; ii < 2; ++ii) {
            int it  = w * 2 + ii;
            int row = bm + it * 16 + r15;
            if (row >= M) row = M - 1;           // clamp (never stored)
            const ushort_t* base = A + (size_t)row * K + k0 + q * 8;
            #pragma unroll
            for (int c = 0; c < 2; ++c)
                ra[ii][c] = *(const u4*)(base + c * 32);
        }
        #pragma unroll
        for (int jj = 0; jj < BT_PW; ++jj) {
            int jt  = w * BT_PW + jj;
            int col = bn + jt * 16 + r15;        // Fo multiple of BN
            const ushort_t* base = Bt + (size_t)col * K + k0 + q * 8;
            #pragma unroll
            for (int c = 0; c < 2; ++c)
                rb[jj][c] = *(const u4*)(base + c * 32);
        }
    };

    load_step(0);
    for (int step = 0; step < nsteps; ++step) {
        __syncthreads();   // prior frag reads done before LDS overwrite
        #pragma unroll
        for (int ii = 0; ii < 2; ++ii)
            #pragma unroll
            for (int c = 0; c < 2; ++c)
                *(u4*)(Al + (size_t)(w * 2 + ii) * 1024 + c * 512 + l * 8) = ra[ii][c];
        #pragma unroll
        for (int jj = 0; jj < BT_PW; ++jj)
            #pragma unroll
            for (int c = 0; c < 2; ++c)
                *(u4*)(Bl + (size_t)(w * BT_PW + jj) * 1024 + c * 512 + l * 8) = rb[jj][c];
        if (step + 1 < nsteps) load_step(step + 1);   // in flight across MFMAs
        __syncthreads();   // LDS writes visible
        #pragma unroll
        for (int c = 0; c < 2; ++c) {            // chunked: caps live frag regs
            v8s af[4], bf[NT];
            #pragma unroll
            for (int mt = 0; mt < 4; ++mt)
                af[mt] = *(const v8s*)(Al + (size_t)(wm * 4 + mt) * 1024 + c * 512 + l * 8);
            #pragma unroll
            for (int nt = 0; nt < NT; ++nt)
                bf[nt] = *(const v8s*)(Bl + (size_t)(wn * NT + nt) * 1024 + c * 512 + l * 8);
            #pragma unroll
            for (int mt = 0; mt < 4; ++mt)
                #pragma unroll
                for (int nt = 0; nt < NT; ++nt)
                    acc[mt][nt] = __builtin_amdgcn_mfma_f32_16x16x32_bf16(
                        af[mt], bf[nt], acc[mt][nt], 0, 0, 0);
        }
    }

    // epilogue: C/D map col=lane&15, row=q*4+reg
    #pragma unroll
    for (int nt = 0; nt < NT; ++nt) {
        int col = bn + wn * (NT * 16) + nt * 16 + r15;
        float bb = bias[col];
        #pragma unroll
        for (int mt = 0; mt < 4; ++mt) {
            #pragma unroll
            for (int p = 0; p < 4; ++p) {
                int row = bm + wm * 64 + mt * 16 + q * 4 + p;
                if (row < M) {
                    float v = acc[mt][nt][p] + bb;
                    if (relu) v = fmaxf(v, 0.0f);
                    if (out_bf16) ((ushort_t*)outp)[(size_t)row * Fo + col] = f2bf(v);
                    else          ((float*)outp)[(size_t)row * Fo + col]   = v;
                }
            }
        }
    }
}

// ------- FUSED fc(512->128) + LayerNorm + ReLU + x_atom + pool ------------------
__global__ __launch_bounds__(256, 2)
void fc_ln_pool_kernel(const ushort_t* __restrict__ A,     // h3 [M][512]
                       const ushort_t* __restrict__ Bt,    // wfc_t [128][512]
                       const float* __restrict__ bias,
                       const float* __restrict__ gamma,
                       const float* __restrict__ beta,
                       const int* __restrict__ batch,
                       float* __restrict__ x_atom,
                       float* __restrict__ pooled)
{
    constexpr int K = 512;
    constexpr int ZS = 133;                       // padded row stride (f32)
    __shared__ __align__(16) char smem[128 * ZS * 4 + 2 * 128 * 4];
    ushort_t* Al = (ushort_t*)smem;               // 8 KB   (K-loop phase)
    ushort_t* Bl = (ushort_t*)(smem + 8192);      // 8 KB   (K-loop phase)
    float*    zt = (float*)smem;                  // 128x133 (epilogue phase)
    float*  mu_s = (float*)(smem + 128 * ZS * 4);
    float*  rs_s = mu_s + 128;

    const int tid = (int)threadIdx.x;
    const int l   = tid & 63;
    const int w   = tid >> 6;
    const int q   = l >> 4;
    const int r15 = l & 15;
    const int bm  = blockIdx.x * 128;
    const int wm  = w >> 1, wn = w & 1;

    const int nsteps = K >> 5;                    // 16

    v4f acc[4][4];
    #pragma unroll
    for (int mt = 0; mt < 4; ++mt)
        #pragma unroll
        for (int nt = 0; nt < 4; ++nt)
            acc[mt][nt] = (v4f){0.0f, 0.0f, 0.0f, 0.0f};

    u4 ra[2], rb[2];
    auto load_step = [&](int step) {
        const int k0 = step << 5;
        #pragma unroll
        for (int ii = 0; ii < 2; ++ii) {
            int it  = w * 2 + ii;
            int row = bm + it * 16 + r15;
            if (row < N_NODES) ra[ii] = *(const u4*)(A + (size_t)row * K + k0 + q * 8);
            else               ra[ii] = (u4){0u, 0u, 0u, 0u};
        }
        #pragma unroll
        for (int jj = 0; jj < 2; ++jj) {
            int jt  = w * 2 + jj;
            int col = jt * 16 + r15;
            rb[jj] = *(const u4*)(Bt + (size_t)col * K + k0 + q * 8);
        }
    };

    load_step(0);
    for (int step = 0; step < nsteps; ++step) {
        __syncthreads();
        #pragma unroll
        for (int ii = 0; ii < 2; ++ii)
            *(u4*)(Al + (size_t)(w * 2 + ii) * 512 + l * 8) = ra[ii];
        #pragma unroll
        for (int jj = 0; jj < 2; ++jj)
            *(u4*)(Bl + (size_t)(w * 2 + jj) * 512 + l * 8) = rb[jj];
        if (step + 1 < nsteps) load_step(step + 1);
        __syncthreads();
        v8s af[4], bf[4];
        #pragma unroll
        for (int mt = 0; mt < 4; ++mt)
            af[mt] = *(const v8s*)(Al + (size_t)(wm * 4 + mt) * 512 + l * 8);
        #pragma unroll
        for (int nt = 0; nt < 4; ++nt)
            bf[nt] = *(const v8s*)(Bl + (size_t)(wn * 4 + nt) * 512 + l * 8);
        #pragma unroll
        for (int mt = 0; mt < 4; ++mt)
            #pragma unroll
            for (int nt = 0; nt < 4; ++nt)
                acc[mt][nt] = __builtin_amdgcn_mfma_f32_16x16x32_bf16(
                    af[mt], bf[nt], acc[mt][nt], 0, 0, 0);
    }

    __syncthreads();         // staging LDS dead -> reuse as zt
    #pragma unroll
    for (int nt = 0; nt < 4; ++nt) {
        int col = wn * 64 + nt * 16 + r15;
        float bb = bias[col];
        #pragma unroll
        for (int mt = 0; mt < 4; ++mt) {
            #pragma unroll
            for (int p = 0; p < 4; ++p) {
                int rr = wm * 64 + mt * 16 + q * 4 + p;
                zt[rr * ZS + col] = acc[mt][nt][p] + bb;
            }
        }
    }
    __syncthreads();
    if (tid < 128) {
        const float* zr = zt + tid * ZS;
        float s = 0.0f;
        for (int j = 0; j < 128; ++j) s += zr[j];
        float m = s * (1.0f / 128.0f);
        float v = 0.0f;
        for (int j = 0; j < 128; ++j) { float d = zr[j] - m; v += d * d; }
        mu_s[tid] = m;
        rs_s[tid] = rsqrtf(v * (1.0f / 128.0f) + 1e-5f);
    }
    __syncthreads();
    for (int i = tid; i < 128 * 128; i += 256) {
        int r = i >> 7, c = i & 127;
        int row = bm + r;
        if (row < N_NODES) {
            float y = (zt[r * ZS + c] - mu_s[r]) * rs_s[r] * gamma[c] + beta[c];
            y = fmaxf(y, 0.0f);
            x_atom[(size_t)row * 128 + c] = y;
            int b = batch[row];
            if ((unsigned)b < (unsigned)N_GRAPHS)
                atomicAdd(pooled + (size_t)b * 128 + c, y);
        }
    }
}

extern "C" void kernel_launch(void* const* d_in, const int* in_sizes, int n_in,
                              void* d_out, int out_size, void* d_ws, size_t ws_size,
                              hipStream_t stream)
{
    const float* x     = (const float*)d_in[0];
    const int*   ei    = (const int*)d_in[1];
    const int*   batch = (const int*)d_in[2];
    const float* W1r   = (const float*)d_in[3];
    const float* b1    = (const float*)d_in[4];
    const float* W1o   = (const float*)d_in[5];
    const float* W2r   = (const float*)d_in[6];
    const float* b2    = (const float*)d_in[7];
    const float* W2o   = (const float*)d_in[8];
    const float* W3r   = (const float*)d_in[9];
    const float* b3    = (const float*)d_in[10];
    const float* W3o   = (const float*)d_in[11];
    const float* Wfc   = (const float*)d_in[12];
    const float* bfc   = (const float*)d_in[13];
    const float* lng   = (const float*)d_in[14];
    const float* lnb   = (const float*)d_in[15];

    const size_t WS_NEED = 204800000;
    if (ws_size < WS_NEED) {
        hipMemsetAsync(d_out, 0, (size_t)out_size * sizeof(float), stream);
        return;
    }

    char* ws = (char*)d_ws;
    // layout (bytes): xb 50000x128 bf16 = 12.8e6 | h1 25.6e6 | aggr 51.2e6
    //                 h2 51.2e6 | h3 51.2e6 | ints | weights
    ushort_t* xb   = (ushort_t*)(ws + 0);
    ushort_t* h1   = (ushort_t*)(ws + 12800000);
    ushort_t* aggr = (ushort_t*)(ws + 38400000);
    ushort_t* h2   = (ushort_t*)(ws + 89600000);
    ushort_t* h3   = (ushort_t*)(ws + 140800000);
    int* deg    = (int*)(ws + 192000000);            // 50000
    int* rowptr = (int*)(ws + 192200000);            // 50001
    int* cursor = (int*)(ws + 192400128);            // 50000
    int* csrsrc = (int*)(ws + 192600128);            // 800000
    int* blksum = (int*)(ws + 195800128);            // 64
    ushort_t* wt = (ushort_t*)(ws + 195800512);      // 917504 elems = 1.835e6 B
    ushort_t* w1r_t = wt;                 // 256x128
    ushort_t* w1o_t = wt + 32768;         // 256x128
    ushort_t* w2r_t = wt + 65536;         // 512x256
    ushort_t* w2o_t = wt + 196608;        // 512x256
    ushort_t* w3r_t = wt + 327680;        // 512x512
    ushort_t* w3o_t = wt + 589824;        // 512x512
    ushort_t* wfc_t = wt + 851968;        // 128x512

    float* x_atom = (float*)d_out;
    float* pooled = x_atom + (size_t)N_NODES * OUT_DIM;

    const int* src = ei;
    const int* dst = ei + N_EDGES;

    // ---- conversions: all weights in ONE launch; x pad+cast ----
    wt_all_kernel<<<(917504 + 255) / 256, 256, 0, stream>>>(W1r, W1o, W2r, W2o,
                                                            W3r, W3o, Wfc, wt);
    pad_cast_kernel<<<((N_NODES * K1P) + 255) / 256, 256, 0, stream>>>(x, xb, N_NODES, IN_DIM, K1P);

    // ---- CSR build ----
    hipMemsetAsync(deg, 0, N_NODES * sizeof(int), stream);
    hist_kernel<<<(N_EDGES + 255) / 256, 256, 0, stream>>>(dst, deg, N_EDGES);
    {
        int nb = (N_NODES + 1023) / 1024;   // 49
        scan1_kernel<<<nb, 1024, 0, stream>>>(deg, rowptr, blksum, N_NODES);
        scan2_kernel<<<1, 64, 0, stream>>>(blksum, nb);
        scan3_kernel<<<(N_NODES + 1 + 255) / 256, 256, 0, stream>>>(blksum, rowptr, cursor, N_NODES);
    }
    fill_kernel<<<(N_EDGES + 255) / 256, 256, 0, stream>>>(src, dst, cursor, csrsrc, N_EDGES);

    const int GY = (N_NODES + 127) / 128;     // 391
    const int AGG_BLKS = (N_NODES + 3) / 4;

    // ---- layer 1: 78(pad128) -> 256 ----
    csr_agg_wave_kernel<2><<<AGG_BLKS, 256, 0, stream>>>(xb, rowptr, csrsrc, aggr, K1P);
    {
        dim3 g(HID / 256, GY);
        mfma_gemm_kernel<8><<<g, 256, 0, stream>>>(aggr, xb, w1r_t, w1o_t, b1, h1,
                                                   N_NODES, K1P, HID, 1, 1);
    }
    // ---- layer 2: 256 -> 512 ----
    csr_agg_wave_kernel<4><<<AGG_BLKS, 256, 0, stream>>>(h1, rowptr, csrsrc, aggr, HID);
    {
        dim3 g((2 * HID) / 256, GY);
        mfma_gemm_kernel<8><<<g, 256, 0, stream>>>(aggr, h1, w2r_t, w2o_t, b2, h2,
                                                   N_NODES, HID, 2 * HID, 1, 1);
    }
    // ---- layer 3: 512 -> 512 ----
    csr_agg_wave_kernel<8><<<AGG_BLKS, 256, 0, stream>>>(h2, rowptr, csrsrc, aggr, 2 * HID);
    {
        dim3 g((2 * HID) / 256, GY);
        mfma_gemm_kernel<8><<<g, 256, 0, stream>>>(aggr, h2, w3r_t, w3o_t, b3, h3,
                                                   N_NODES, 2 * HID, 2 * HID, 1, 1);
    }
    // ---- fused fc + LN + ReLU + pool ----
    hipMemsetAsync(pooled, 0, (size_t)N_GRAPHS * OUT_DIM * sizeof(float), stream);
    fc_ln_pool_kernel<<<GY, 256, 0, stream>>>(h3, wfc_t, bfc, lng, lnb, batch,
                                              x_atom, pooled);
}

// Round 13
// 692.865 us; speedup vs baseline: 1.0306x; 1.0306x over previous
//
#include <hip/hip_runtime.h>

#define N_NODES 50000
#define N_EDGES 800000
#define N_GRAPHS 1024
#define IN_DIM 78
#define K1P 96            // IN_DIM padded to multiple of 32
#define HID 256
#define OUT_DIM 128

typedef unsigned short ushort_t;
typedef __attribute__((ext_vector_type(8))) short v8s;
typedef __attribute__((ext_vector_type(4))) float v4f;
typedef __attribute__((ext_vector_type(4))) unsigned int u4;
typedef __attribute__((ext_vector_type(2))) unsigned short us2;
typedef __attribute__((ext_vector_type(4))) unsigned short us4;
typedef __attribute__((ext_vector_type(8))) unsigned short us8;

__device__ __forceinline__ ushort_t f2bf(float f) {
    unsigned u = __float_as_uint(f);
    unsigned r = (u + 0x7fffu + ((u >> 16) & 1u)) >> 16;   // RNE
    return (ushort_t)r;
}
__device__ __forceinline__ float bf2f(ushort_t h) {
    return __uint_as_float((unsigned)h << 16);
}

// ------------- fused weight transpose+pad+bf16 for ALL weights (1 launch) ------
__global__ __launch_bounds__(256)
void wt_all_kernel(const float* __restrict__ W1r, const float* __restrict__ W1o,
                   const float* __restrict__ W2r, const float* __restrict__ W2o,
                   const float* __restrict__ W3r, const float* __restrict__ W3o,
                   const float* __restrict__ Wfc, ushort_t* __restrict__ out)
{
    int i = blockIdx.x * 256 + threadIdx.x;
    if (i >= 901120) return;
    const float* W; int K, N, Kp, base;
    if      (i < 24576)  { W = W1r; K = IN_DIM; N = HID;     Kp = 96;  base = 0; }
    else if (i < 49152)  { W = W1o; K = IN_DIM; N = HID;     Kp = 96;  base = 24576; }
    else if (i < 180224) { W = W2r; K = HID;    N = 2 * HID; Kp = 256; base = 49152; }
    else if (i < 311296) { W = W2o; K = HID;    N = 2 * HID; Kp = 256; base = 180224; }
    else if (i < 573440) { W = W3r; K = 2*HID;  N = 2 * HID; Kp = 512; base = 311296; }
    else if (i < 835584) { W = W3o; K = 2*HID;  N = 2 * HID; Kp = 512; base = 573440; }
    else                 { W = Wfc; K = 2*HID;  N = OUT_DIM; Kp = 512; base = 835584; }
    int j = i - base;
    int n = j / Kp, k = j - n * Kp;
    float v = (k < K) ? W[(size_t)k * N + n] : 0.0f;
    out[i] = f2bf(v);
}

// ---------------- pad + cast activations: out[r][k<Kin?]=in, else 0 -----------
__global__ __launch_bounds__(256)
void pad_cast_kernel(const float* __restrict__ in, ushort_t* __restrict__ out,
                     int rows, int Kin, int Kout)
{
    int i = blockIdx.x * 256 + threadIdx.x;
    if (i >= rows * Kout) return;
    int r = i / Kout, k = i - r * Kout;
    out[i] = f2bf(k < Kin ? in[(size_t)r * Kin + k] : 0.0f);
}

// ---------------- CSR build ----------------------------------------------------
__global__ __launch_bounds__(256)
void hist_kernel(const int* __restrict__ dstI, int* __restrict__ deg, int nE)
{
    int e = blockIdx.x * 256 + threadIdx.x;
    if (e < nE) {
        int d = dstI[e];
        if ((unsigned)d < (unsigned)N_NODES) atomicAdd(&deg[d], 1);
    }
}

__global__ __launch_bounds__(1024)
void scan1_kernel(const int* __restrict__ deg, int* __restrict__ rowptr,
                  int* __restrict__ blocksum, int n)
{
    __shared__ int s[1024];
    int b = (int)blockIdx.x, t = (int)threadIdx.x;
    int i = b * 1024 + t;
    int v = (i < n) ? deg[i] : 0;
    s[t] = v;
    __syncthreads();
    for (int off = 1; off < 1024; off <<= 1) {
        int a = (t >= off) ? s[t - off] : 0;
        __syncthreads();
        s[t] += a;
        __syncthreads();
    }
    if (i < n) rowptr[i + 1] = s[t];      // block-local inclusive
    if (t == 1023) blocksum[b] = s[1023];
    if (b == 0 && t == 0) rowptr[0] = 0;
}

__global__ __launch_bounds__(64)
void scan2_kernel(int* __restrict__ blocksum, int nb)   // nb <= 64
{
    int t = (int)threadIdx.x;
    int v = (t < nb) ? blocksum[t] : 0;
    #pragma unroll
    for (int off = 1; off < 64; off <<= 1) {
        int a = __shfl_up(v, off, 64);
        if (t >= off) v += a;
    }
    if (t < nb) blocksum[t] = v;
}

__global__ __launch_bounds__(256)
void scan3_kernel(const int* __restrict__ blocksum, int* __restrict__ rowptr,
                  int* __restrict__ cursor, int n)
{
    int j = blockIdx.x * 256 + threadIdx.x;   // 0..n
    if (j > n) return;
    int v;
    if (j == 0) v = 0;
    else {
        int b = (j - 1) >> 10;
        v = rowptr[j] + (b >= 1 ? blocksum[b - 1] : 0);
    }
    rowptr[j] = v;
    if (j < n) cursor[j] = v;
}

__global__ __launch_bounds__(256)
void fill_kernel(const int* __restrict__ srcI, const int* __restrict__ dstI,
                 int* __restrict__ cursor, int* __restrict__ csr_src, int nE)
{
    int e = blockIdx.x * 256 + threadIdx.x;
    if (e < nE) {
        int d = dstI[e];
        int s = srcI[e];
        if ((unsigned)d < (unsigned)N_NODES && (unsigned)s < (unsigned)N_NODES) {
            int pos = atomicAdd(&cursor[d], 1);
            csr_src[pos] = s;
        }
    }
}

// ---------------- CSR aggregation, wave-per-node, 8-deep load pipeline ----------
template<int VPT> struct VecT;
template<> struct VecT<2> { using T = us2; };
template<> struct VecT<4> { using T = us4; };
template<> struct VecT<8> { using T = us8; };

template<int VPT>
__global__ __launch_bounds__(256)
void csr_agg_wave_kernel(const ushort_t* __restrict__ feat,
                         const int* __restrict__ rowptr,
                         const int* __restrict__ csr_src,
                         ushort_t* __restrict__ out, int Ds)
{
    using T = typename VecT<VPT>::T;
    const int wv   = (int)threadIdx.x >> 6;
    const int node = (int)blockIdx.x * 4 + wv;
    if (node >= N_NODES) return;
    const int lane = (int)threadIdx.x & 63;
    const int off0 = lane * VPT;
    const bool act = off0 < Ds;
    const int off  = act ? off0 : (Ds - VPT);

    const int e0 = rowptr[node], e1 = rowptr[node + 1];
    float acc[VPT];
    #pragma unroll
    for (int i = 0; i < VPT; ++i) acc[i] = 0.0f;

    int e = e0;
    for (; e + 8 <= e1; e += 8) {
        T r[8];
        #pragma unroll
        for (int u = 0; u < 8; ++u) {
            int s = csr_src[e + u];
            r[u] = *(const T*)(feat + (size_t)s * Ds + off);
        }
        #pragma unroll
        for (int u = 0; u < 8; ++u)
            #pragma unroll
            for (int i = 0; i < VPT; ++i) acc[i] += bf2f(r[u][i]);
    }
    for (; e + 4 <= e1; e += 4) {
        T r[4];
        #pragma unroll
        for (int u = 0; u < 4; ++u) {
            int s = csr_src[e + u];
            r[u] = *(const T*)(feat + (size_t)s * Ds + off);
        }
        #pragma unroll
        for (int u = 0; u < 4; ++u)
            #pragma unroll
            for (int i = 0; i < VPT; ++i) acc[i] += bf2f(r[u][i]);
    }
    for (; e < e1; ++e) {
        int s = csr_src[e];
        T r = *(const T*)(feat + (size_t)s * Ds + off);
        #pragma unroll
        for (int i = 0; i < VPT; ++i) acc[i] += bf2f(r[i]);
    }

    if (act) {
        T o;
        #pragma unroll
        for (int i = 0; i < VPT; ++i) o[i] = f2bf(acc[i]);
        *(T*)(out + (size_t)node * Ds + off0) = o;
    }
}

// ---------------- bf16 MFMA GEMM, r8 K-loop + XCD-pairing block swizzle ---------
// out = act( A1@W1t^T + A2@W2t^T + bias ),  A*: bf16 [M][K], W*t: bf16 [Fo][K]
// Tile: 128 rows x (NT*32) cols, BK=32. 4 waves 2x2; wave = 64 x NT*16.
// 1D grid, swizzled so the 2 col-blocks of a row-stripe get IDs congruent
// mod 8 (supergroups of 8 rows x 2 cols = 16 IDs): under round-robin
// blockIdx->XCD dispatch both land on the SAME XCD and share the A-stripe
// (256 KB) + sibling B-stripes in that XCD's 4 MB L2 instead of pulling
// from L3 twice. Harmless if the mapping heuristic doesn't hold.
template<int NT>
__global__ __launch_bounds__(256, 2)
void mfma_gemm_kernel(const ushort_t* __restrict__ A1,
                      const ushort_t* __restrict__ A2,
                      const ushort_t* __restrict__ W1t,
                      const ushort_t* __restrict__ W2t,
                      const float* __restrict__ bias,
                      void* __restrict__ outp,
                      int M, int K, int Fo, int relu, int out_bf16)
{
    constexpr int BN    = NT * 32;     // tile width
    constexpr int NBT   = NT * 2;      // B n-tiles of 16
    constexpr int BT_PW = NBT / 4;     // B-tiles staged per wave
    __shared__ __align__(16) ushort_t Al[8 * 512];   // 8 m-tiles, lane-ordered
    __shared__ __align__(16) ushort_t Bl[NBT * 512];
    const int tid = (int)threadIdx.x;
    const int l   = tid & 63;
    const int w   = tid >> 6;
    const int q   = l >> 4;
    const int r15 = l & 15;

    // --- XCD-pairing swizzle (1D grid = ncol * gy) ---
    const int ncol = Fo / BN;                 // 1 or 2
    const int gy   = (int)gridDim.x / ncol;
    int bxi, byi;
    {
        int b = (int)blockIdx.x;
        if (ncol == 2) {
            int fullRows   = (gy >> 3) << 3;
            int fullBlocks = fullRows * 2;
            if (b < fullBlocks) {
                int g = b >> 4, r = b & 15;
                byi = g * 8 + (r & 7);
                bxi = r >> 3;
            } else {
                int r = b - fullBlocks;
                int tail = gy - fullRows;     // 1..7
                byi = fullRows + (r % tail);
                bxi = r / tail;
            }
        } else {
            bxi = 0;
            byi = b;
        }
    }
    const int bm  = byi * 128;
    const int bn  = bxi * BN;
    const int wm  = w >> 1, wn = w & 1;

    const int s1 = K >> 5;                       // steps per pass
    const int nsteps = A2 ? (2 * s1) : s1;

    v4f acc[4][NT];
    #pragma unroll
    for (int mt = 0; mt < 4; ++mt)
        #pragma unroll
        for (int nt = 0; nt < NT; ++nt)
            acc[mt][nt] = (v4f){0.0f, 0.0f, 0.0f, 0.0f};

    u4 ra[2], rb[BT_PW];
    auto load_step = [&](int step) {
        const ushort_t* A  = (step >= s1) ? A2  : A1;
        const ushort_t* Bt = (step >= s1) ? W2t : W1t;
        const int k0 = ((step >= s1) ? (step - s1) : step) << 5;
        #pragma unroll
        for (int ii = 0; ii < 2; ++ii) {
            int it  = w * 2 + ii;
            int row = bm + it * 16 + r15;
            if (row < M) ra[ii] = *(const u4*)(A + (size_t)row * K + k0 + q * 8);
            else         ra[ii] = (u4){0u, 0u, 0u, 0u};
        }
        #pragma unroll
        for (int jj = 0; jj < BT_PW; ++jj) {
            int jt  = w * BT_PW + jj;
            int col = bn + jt * 16 + r15;          // Fo multiple of BN
            rb[jj] = *(const u4*)(Bt + (size_t)col * K + k0 + q * 8);
        }
    };

    load_step(0);
    for (int step = 0; step < nsteps; ++step) {
        __syncthreads();   // prior frag reads done before LDS overwrite
        #pragma unroll
        for (int ii = 0; ii < 2; ++ii)
            *(u4*)(Al + (size_t)(w * 2 + ii) * 512 + l * 8) = ra[ii];
        #pragma unroll
        for (int jj = 0; jj < BT_PW; ++jj)
            *(u4*)(Bl + (size_t)(w * BT_PW + jj) * 512 + l * 8) = rb[jj];
        if (step + 1 < nsteps) load_step(step + 1);   // in flight across MFMAs
        __syncthreads();   // LDS writes visible
        v8s af[4], bf[NT];
        #pragma unroll
        for (int mt = 0; mt < 4; ++mt)
            af[mt] = *(const v8s*)(Al + (size_t)(wm * 4 + mt) * 512 + l * 8);
        #pragma unroll
        for (int nt = 0; nt < NT; ++nt)
            bf[nt] = *(const v8s*)(Bl + (size_t)(wn * NT + nt) * 512 + l * 8);
        #pragma unroll
        for (int mt = 0; mt < 4; ++mt)
            #pragma unroll
            for (int nt = 0; nt < NT; ++nt)
                acc[mt][nt] = __builtin_amdgcn_mfma_f32_16x16x32_bf16(
                    af[mt], bf[nt], acc[mt][nt], 0, 0, 0);
    }

    // epilogue: C/D map col=lane&15, row=q*4+reg
    #pragma unroll
    for (int nt = 0; nt < NT; ++nt) {
        int col = bn + wn * (NT * 16) + nt * 16 + r15;
        float bb = bias[col];
        #pragma unroll
        for (int mt = 0; mt < 4; ++mt) {
            #pragma unroll
            for (int p = 0; p < 4; ++p) {
                int row = bm + wm * 64 + mt * 16 + q * 4 + p;
                if (row < M) {
                    float v = acc[mt][nt][p] + bb;
                    if (relu) v = fmaxf(v, 0.0f);
                    if (out_bf16) ((ushort_t*)outp)[(size_t)row * Fo + col] = f2bf(v);
                    else          ((float*)outp)[(size_t)row * Fo + col]   = v;
                }
            }
        }
    }
}

// ------- FUSED fc(512->128) + LayerNorm + ReLU + x_atom + pool ------------------
__global__ __launch_bounds__(256, 2)
void fc_ln_pool_kernel(const ushort_t* __restrict__ A,     // h3 [M][512]
                       const ushort_t* __restrict__ Bt,    // wfc_t [128][512]
                       const float* __restrict__ bias,
                       const float* __restrict__ gamma,
                       const float* __restrict__ beta,
                       const int* __restrict__ batch,
                       float* __restrict__ x_atom,
                       float* __restrict__ pooled)
{
    constexpr int K = 512;
    constexpr int ZS = 133;                       // padded row stride (f32)
    __shared__ __align__(16) char smem[128 * ZS * 4 + 2 * 128 * 4];
    ushort_t* Al = (ushort_t*)smem;               // 8 KB   (K-loop phase)
    ushort_t* Bl = (ushort_t*)(smem + 8192);      // 8 KB   (K-loop phase)
    float*    zt = (float*)smem;                  // 128x133 (epilogue phase)
    float*  mu_s = (float*)(smem + 128 * ZS * 4);
    float*  rs_s = mu_s + 128;

    const int tid = (int)threadIdx.x;
    const int l   = tid & 63;
    const int w   = tid >> 6;
    const int q   = l >> 4;
    const int r15 = l & 15;
    const int bm  = blockIdx.x * 128;
    const int wm  = w >> 1, wn = w & 1;

    const int nsteps = K >> 5;                    // 16

    v4f acc[4][4];
    #pragma unroll
    for (int mt = 0; mt < 4; ++mt)
        #pragma unroll
        for (int nt = 0; nt < 4; ++nt)
            acc[mt][nt] = (v4f){0.0f, 0.0f, 0.0f, 0.0f};

    u4 ra[2], rb[2];
    auto load_step = [&](int step) {
        const int k0 = step << 5;
        #pragma unroll
        for (int ii = 0; ii < 2; ++ii) {
            int it  = w * 2 + ii;
            int row = bm + it * 16 + r15;
            if (row < N_NODES) ra[ii] = *(const u4*)(A + (size_t)row * K + k0 + q * 8);
            else               ra[ii] = (u4){0u, 0u, 0u, 0u};
        }
        #pragma unroll
        for (int jj = 0; jj < 2; ++jj) {
            int jt  = w * 2 + jj;
            int col = jt * 16 + r15;
            rb[jj] = *(const u4*)(Bt + (size_t)col * K + k0 + q * 8);
        }
    };

    load_step(0);
    for (int step = 0; step < nsteps; ++step) {
        __syncthreads();
        #pragma unroll
        for (int ii = 0; ii < 2; ++ii)
            *(u4*)(Al + (size_t)(w * 2 + ii) * 512 + l * 8) = ra[ii];
        #pragma unroll
        for (int jj = 0; jj < 2; ++jj)
            *(u4*)(Bl + (size_t)(w * 2 + jj) * 512 + l * 8) = rb[jj];
        if (step + 1 < nsteps) load_step(step + 1);
        __syncthreads();
        v8s af[4], bf[4];
        #pragma unroll
        for (int mt = 0; mt < 4; ++mt)
            af[mt] = *(const v8s*)(Al + (size_t)(wm * 4 + mt) * 512 + l * 8);
        #pragma unroll
        for (int nt = 0; nt < 4; ++nt)
            bf[nt] = *(const v8s*)(Bl + (size_t)(wn * 4 + nt) * 512 + l * 8);
        #pragma unroll
        for (int mt = 0; mt < 4; ++mt)
            #pragma unroll
            for (int nt = 0; nt < 4; ++nt)
                acc[mt][nt] = __builtin_amdgcn_mfma_f32_16x16x32_bf16(
                    af[mt], bf[nt], acc[mt][nt], 0, 0, 0);
    }

    __syncthreads();         // staging LDS dead -> reuse as zt
    #pragma unroll
    for (int nt = 0; nt < 4; ++nt) {
        int col = wn * 64 + nt * 16 + r15;
        float bb = bias[col];
        #pragma unroll
        for (int mt = 0; mt < 4; ++mt) {
            #pragma unroll
            for (int p = 0; p < 4; ++p) {
                int rr = wm * 64 + mt * 16 + q * 4 + p;
                zt[rr * ZS + col] = acc[mt][nt][p] + bb;
            }
        }
    }
    __syncthreads();
    if (tid < 128) {
        const float* zr = zt + tid * ZS;
        float s = 0.0f;
        for (int j = 0; j < 128; ++j) s += zr[j];
        float m = s * (1.0f / 128.0f);
        float v = 0.0f;
        for (int j = 0; j < 128; ++j) { float d = zr[j] - m; v += d * d; }
        mu_s[tid] = m;
        rs_s[tid] = rsqrtf(v * (1.0f / 128.0f) + 1e-5f);
    }
    __syncthreads();
    for (int i = tid; i < 128 * 128; i += 256) {
        int r = i >> 7, c = i & 127;
        int row = bm + r;
        if (row < N_NODES) {
            float y = (zt[r * ZS + c] - mu_s[r]) * rs_s[r] * gamma[c] + beta[c];
            y = fmaxf(y, 0.0f);
            x_atom[(size_t)row * 128 + c] = y;
            int b = batch[row];
            if ((unsigned)b < (unsigned)N_GRAPHS)
                atomicAdd(pooled + (size_t)b * 128 + c, y);
        }
    }
}

extern "C" void kernel_launch(void* const* d_in, const int* in_sizes, int n_in,
                              void* d_out, int out_size, void* d_ws, size_t ws_size,
                              hipStream_t stream)
{
    const float* x     = (const float*)d_in[0];
    const int*   ei    = (const int*)d_in[1];
    const int*   batch = (const int*)d_in[2];
    const float* W1r   = (const float*)d_in[3];
    const float* b1    = (const float*)d_in[4];
    const float* W1o   = (const float*)d_in[5];
    const float* W2r   = (const float*)d_in[6];
    const float* b2    = (const float*)d_in[7];
    const float* W2o   = (const float*)d_in[8];
    const float* W3r   = (const float*)d_in[9];
    const float* b3    = (const float*)d_in[10];
    const float* W3o   = (const float*)d_in[11];
    const float* Wfc   = (const float*)d_in[12];
    const float* bfc   = (const float*)d_in[13];
    const float* lng   = (const float*)d_in[14];
    const float* lnb   = (const float*)d_in[15];

    const size_t WS_NEED = 204800000;
    if (ws_size < WS_NEED) {
        hipMemsetAsync(d_out, 0, (size_t)out_size * sizeof(float), stream);
        return;
    }

    char* ws = (char*)d_ws;
    ushort_t* xb   = (ushort_t*)(ws + 0);            // 50000x96 bf16
    ushort_t* h1   = (ushort_t*)(ws + 9600000);      // 50000x256 bf16
    ushort_t* aggr = (ushort_t*)(ws + 35200000);     // up to 50000x512 bf16
    ushort_t* h2   = (ushort_t*)(ws + 86400000);     // 50000x512 bf16
    ushort_t* h3   = (ushort_t*)(ws + 137600000);    // 50000x512 bf16
    int* deg    = (int*)(ws + 188800000);            // 50000
    int* rowptr = (int*)(ws + 189000000);            // 50001
    int* cursor = (int*)(ws + 189200128);            // 50000
    int* csrsrc = (int*)(ws + 189400128);            // 800000
    int* blksum = (int*)(ws + 192600128);            // 64
    ushort_t* wt = (ushort_t*)(ws + 192600512);
    ushort_t* w1r_t = wt;                 // 256x96   @0
    ushort_t* w1o_t = wt + 24576;         // 256x96
    ushort_t* w2r_t = wt + 49152;         // 512x256
    ushort_t* w2o_t = wt + 180224;        // 512x256
    ushort_t* w3r_t = wt + 311296;        // 512x512
    ushort_t* w3o_t = wt + 573440;        // 512x512
    ushort_t* wfc_t = wt + 835584;        // 128x512

    float* x_atom = (float*)d_out;
    float* pooled = x_atom + (size_t)N_NODES * OUT_DIM;

    const int* src = ei;
    const int* dst = ei + N_EDGES;

    // ---- conversions: all weights in ONE launch; x pad+cast ----
    wt_all_kernel<<<(901120 + 255) / 256, 256, 0, stream>>>(W1r, W1o, W2r, W2o,
                                                            W3r, W3o, Wfc, wt);
    pad_cast_kernel<<<((N_NODES * K1P) + 255) / 256, 256, 0, stream>>>(x, xb, N_NODES, IN_DIM, K1P);

    // ---- CSR build ----
    hipMemsetAsync(deg, 0, N_NODES * sizeof(int), stream);
    hist_kernel<<<(N_EDGES + 255) / 256, 256, 0, stream>>>(dst, deg, N_EDGES);
    {
        int nb = (N_NODES + 1023) / 1024;   // 49
        scan1_kernel<<<nb, 1024, 0, stream>>>(deg, rowptr, blksum, N_NODES);
        scan2_kernel<<<1, 64, 0, stream>>>(blksum, nb);
        scan3_kernel<<<(N_NODES + 1 + 255) / 256, 256, 0, stream>>>(blksum, rowptr, cursor, N_NODES);
    }
    fill_kernel<<<(N_EDGES + 255) / 256, 256, 0, stream>>>(src, dst, cursor, csrsrc, N_EDGES);

    const int GY = (N_NODES + 127) / 128;     // 391
    const int AGG_BLKS = (N_NODES + 3) / 4;

    // ---- layer 1: 78(pad96) -> 256 ----
    csr_agg_wave_kernel<2><<<AGG_BLKS, 256, 0, stream>>>(xb, rowptr, csrsrc, aggr, K1P);
    {
        mfma_gemm_kernel<8><<<(HID / 256) * GY, 256, 0, stream>>>(
            aggr, xb, w1r_t, w1o_t, b1, h1, N_NODES, K1P, HID, 1, 1);
    }
    // ---- layer 2: 256 -> 512 ----
    csr_agg_wave_kernel<4><<<AGG_BLKS, 256, 0, stream>>>(h1, rowptr, csrsrc, aggr, HID);
    {
        mfma_gemm_kernel<8><<<((2 * HID) / 256) * GY, 256, 0, stream>>>(
            aggr, h1, w2r_t, w2o_t, b2, h2, N_NODES, HID, 2 * HID, 1, 1);
    }
    // ---- layer 3: 512 -> 512 ----
    csr_agg_wave_kernel<8><<<AGG_BLKS, 256, 0, stream>>>(h2, rowptr, csrsrc, aggr, 2 * HID);
    {
        mfma_gemm_kernel<8><<<((2 * HID) / 256) * GY, 256, 0, stream>>>(
            aggr, h2, w3r_t, w3o_t, b3, h3, N_NODES, 2 * HID, 2 * HID, 1, 1);
    }
    // ---- fused fc + LN + ReLU + pool ----
    hipMemsetAsync(pooled, 0, (size_t)N_GRAPHS * OUT_DIM * sizeof(float), stream);
    fc_ln_pool_kernel<<<GY, 256, 0, stream>>>(h3, wfc_t, bfc, lng, lnb, batch,
                                              x_atom, pooled);
}